// Round 4
// baseline (318.032 us; speedup 1.0000x reference)
//
#include <hip/hip_runtime.h>

#define DI __device__ __forceinline__

typedef __attribute__((ext_vector_type(8))) short short8v;
typedef __attribute__((ext_vector_type(4))) float f32x4;

static constexpr int B_ = 4, S_ = 2048, D_ = 1024, H_ = 16, HD_ = 64;
static constexpr int M_ = B_ * S_;  // 8192 rows

// f32 -> bf16 round-nearest-even
DI unsigned short f2bf(float f) {
  unsigned u = __builtin_bit_cast(unsigned, f);
  u = (u + 0x7fffu + ((u >> 16) & 1u)) >> 16;
  return (unsigned short)u;
}

DI unsigned cvt_pk_bf16(float lo, float hi) {
  unsigned r;
  asm("v_cvt_pk_bf16_f32 %0, %1, %2" : "=v"(r) : "v"(lo), "v"(hi));
  return r;
}

// async global->LDS, 16B per lane; LDS dest must be wave-uniform base (HW adds lane*16)
DI void async_copy16(const void* g, void* l) {
  __builtin_amdgcn_global_load_lds((const __attribute__((address_space(1))) void*)g,
                                   (__attribute__((address_space(3))) void*)l, 16, 0, 0);
}

// ---------------- elementwise cast f32 -> bf16 (vectorized) ----------------
__global__ __launch_bounds__(256) void cast_bf16_kernel(const float* __restrict__ in,
                                                        unsigned short* __restrict__ out,
                                                        int n4) {
  int i = blockIdx.x * blockDim.x + threadIdx.x;
  int stride = gridDim.x * blockDim.x;
  for (; i < n4; i += stride) {
    float4 v = reinterpret_cast<const float4*>(in)[i];
    ushort4 o;
    o.x = f2bf(v.x); o.y = f2bf(v.y); o.z = f2bf(v.z); o.w = f2bf(v.w);
    reinterpret_cast<ushort4*>(out)[i] = o;
  }
}

// ---------------- transpose + cast weights: W[K,N] f32 -> Wt[N,K] bf16 ----------------
__global__ __launch_bounds__(256) void transpose_cast_kernel(const float* __restrict__ W,
                                                             unsigned short* __restrict__ Wt,
                                                             int n) {
  __shared__ float t[32][33];
  int bx = blockIdx.x * 32, by = blockIdx.y * 32;
  int x = threadIdx.x, y0 = threadIdx.y;
#pragma unroll
  for (int yy = 0; yy < 32; yy += 8)
    t[y0 + yy][x] = W[(long)(by + y0 + yy) * n + bx + x];
  __syncthreads();
#pragma unroll
  for (int yy = 0; yy < 32; yy += 8)
    Wt[(long)(bx + y0 + yy) * n + by + x] = f2bf(t[x][y0 + yy]);
}

// ---------------- pack mask (0/1 f32) into bit words, layout [B][S/64 kt][S q] ----------------
__global__ __launch_bounds__(256) void pack_mask_kernel(const float* __restrict__ mask,
                                                        unsigned long long* __restrict__ bits,
                                                        int nwords) {
  int lane = threadIdx.x & 63;
  int wpb = blockDim.x >> 6;
  int w = blockIdx.x * wpb + (threadIdx.x >> 6);
  int stride = gridDim.x * wpb;
  for (; w < nwords; w += stride) {
    float v = mask[(long)w * 64 + lane];
    unsigned long long b = __ballot(v > 0.5f);
    if (lane == 0) {
      int bb = w >> 16, q = (w >> 5) & 2047, kt64 = w & 31;
      bits[((long)bb << 16) | (kt64 << 11) | q] = b;
    }
  }
}

// ---------------- GEMM: C[M,N] = A[M,K] * Bt[N,K]^T + bias, bf16 MFMA ----------------
// MODE 0: bf16 out [M,N], val=(acc+bias)*scale
// MODE 1: bf16 out as per-head transposed V with key-permuted columns:
//         Vt[(b*16+h)*64+d][perm(s)], perm within each 32-block: p = gg*8 + b4*4 + r
//         for s&31 = b4*16 + gg*4 + r  (so attn's in-register P^T lines up as B-fragment)
// MODE 2: f32 out [M,N]
template <int MODE>
__global__ __launch_bounds__(256) void gemm_bt_kernel(const unsigned short* __restrict__ A,
                                                      const unsigned short* __restrict__ Bt,
                                                      const float* __restrict__ bias,
                                                      void* __restrict__ out,
                                                      int Mdim, int Ndim, int Kdim, float scale) {
  __shared__ unsigned short As[128 * 32];
  __shared__ unsigned short Bs[128 * 32];
  const int tid = threadIdx.x;
  const int lane = tid & 63;
  const int w = tid >> 6;
  const int g = lane >> 4;
  const int l15 = lane & 15;
  const int bm = blockIdx.x * 128;
  const int bn = blockIdx.y * 128;
  const int wr = w >> 1, wc = w & 1;

  f32x4 zero = {0.f, 0.f, 0.f, 0.f};
  f32x4 acc[4][4];
#pragma unroll
  for (int i = 0; i < 4; ++i)
#pragma unroll
    for (int j = 0; j < 4; ++j) acc[i][j] = zero;

  const int srow = lane >> 2;        // 0..15 within 16-row chunk
  const int scol = (lane & 3) * 8;   // bf16 col offset, 8 elems = 16B

  for (int k0 = 0; k0 < Kdim; k0 += 32) {
#pragma unroll
    for (int i = 0; i < 2; ++i) {
      int q = w * 2 + i;             // 1KB chunk index, rows [q*16, q*16+16)
      int row = q * 16 + srow;
      async_copy16(&A[(long)(bm + row) * Kdim + k0 + scol], &As[q * 512]);
      async_copy16(&Bt[(long)(bn + row) * Kdim + k0 + scol], &Bs[q * 512]);
    }
    __syncthreads();
    short8v a[4], b[4];
#pragma unroll
    for (int i = 0; i < 4; ++i)
      a[i] = *reinterpret_cast<const short8v*>(&As[(wr * 64 + i * 16 + l15) * 32 + g * 8]);
#pragma unroll
    for (int j = 0; j < 4; ++j)
      b[j] = *reinterpret_cast<const short8v*>(&Bs[(wc * 64 + j * 16 + l15) * 32 + g * 8]);
#pragma unroll
    for (int i = 0; i < 4; ++i)
#pragma unroll
      for (int j = 0; j < 4; ++j)
        acc[i][j] = __builtin_amdgcn_mfma_f32_16x16x32_bf16(a[i], b[j], acc[i][j], 0, 0, 0);
    __syncthreads();
  }

#pragma unroll
  for (int jj = 0; jj < 4; ++jj) {
    int n = bn + wc * 64 + jj * 16 + l15;
    float bs = bias[n];
#pragma unroll
    for (int i = 0; i < 4; ++i) {
      int m0 = bm + wr * 64 + i * 16 + g * 4;  // rows m0..m0+3 (reg r)
      if (MODE == 0) {
        unsigned short* o = (unsigned short*)out;
#pragma unroll
        for (int r = 0; r < 4; ++r)
          o[(long)(m0 + r) * Ndim + n] = f2bf((acc[i][jj][r] + bs) * scale);
      } else if (MODE == 1) {
        int b2 = m0 >> 11, s0 = m0 & 2047;
        // key permutation within 32-block (see comment above); (s0&3)==0 so 4 elems contiguous
        int s0p = (s0 & ~31) | (((s0 >> 2) & 3) << 3) | (((s0 >> 4) & 1) << 2);
        int h2 = n >> 6, d2 = n & 63;
        unsigned short* o = (unsigned short*)out;
        ushort4 v;
        v.x = f2bf(acc[i][jj][0] + bs);
        v.y = f2bf(acc[i][jj][1] + bs);
        v.z = f2bf(acc[i][jj][2] + bs);
        v.w = f2bf(acc[i][jj][3] + bs);
        *reinterpret_cast<ushort4*>(&o[((long)((b2 * 16 + h2) * 64 + d2) << 11) + s0p]) = v;
      } else {
        float* o = (float*)out;
#pragma unroll
        for (int r = 0; r < 4; ++r)
          o[(long)(m0 + r) * Ndim + n] = acc[i][jj][r] + bs;
      }
    }
  }
}

// ---------------- fused flash attention (v4: double-buffered K/V, counted vmcnt) ----------------
// grid (S/128, B*H), 4 waves; wave w owns q rows qt*128 + w*32 .. +31 (2 q-fragments).
// Per iteration: [prefetch mask(t+1) regs + stage(t+1) -> buf^1] -> vmcnt(6) -> s_barrier ->
// compute(t) from buf -> s_barrier.  vmcnt never drains to 0 in the main loop (T3+T4),
// so the 6 in-flight VMEM ops (2 mask + 4 stage) hide HBM/L2 latency under compute.
__global__ __launch_bounds__(256, 2) void attn_kernel(const unsigned short* __restrict__ Q,   // [B,S,D] pre-scaled log2e/8
                                                      const unsigned short* __restrict__ Kb,  // [B,S,D]
                                                      const unsigned short* __restrict__ Vt,  // [B*H,64,S] key-permuted
                                                      const unsigned long long* __restrict__ mbits, // [B][32][2048]
                                                      unsigned short* __restrict__ attn) {    // [B,S,D]
  __shared__ unsigned short Ks[2][64 * 64];       // swizzled, rows = key
  __shared__ unsigned short Vs[2][64 * 64];       // swizzled, rows = d
  const int lane = threadIdx.x & 63;
  const int w = threadIdx.x >> 6;
  const int g = lane >> 4;
  const int l15 = lane & 15;
  const int qt = blockIdx.x;
  const int bh = blockIdx.y;
  const int b = bh >> 4, h = bh & 15;
  const int q0 = qt * 128 + w * 32 + l15;  // qf=0 row; qf=1 row = q0+16

  // Q fragments double as MFMA B-operand: col n=q=lane&15, k=d=g*8+j (+32)
  const unsigned short* qp = Q + ((long)b * S_ + q0) * D_ + h * HD_ + g * 8;
  short8v qfr[2][2];
  qfr[0][0] = *reinterpret_cast<const short8v*>(qp);
  qfr[0][1] = *reinterpret_cast<const short8v*>(qp + 32);
  qfr[1][0] = *reinterpret_cast<const short8v*>(qp + 16 * D_);
  qfr[1][1] = *reinterpret_cast<const short8v*>(qp + 16 * D_ + 32);

  // staging: LDS chunk c holds global chunk c ^ (row&7)  (inverse-swizzled source)
  const int srow = lane >> 3;
  const int schunk = ((lane & 7) ^ (lane >> 3)) * 8;  // in elements
  const unsigned short* kstage = Kb + (long)b * S_ * D_ + h * HD_;
  const unsigned short* vstage = Vt + (long)bh * HD_ * S_;

  f32x4 zero = {0.f, 0.f, 0.f, 0.f};
  f32x4 oacc[2][4];
#pragma unroll
  for (int qf = 0; qf < 2; ++qf)
#pragma unroll
    for (int d = 0; d < 4; ++d) oacc[qf][d] = zero;
  float m_run[2] = {-1e30f, -1e30f}, l_run[2] = {0.f, 0.f};

  const unsigned long long* mbase = mbits + ((long)b << 16);
  const int swz = l15 & 7;

  // stage tile (kt = tile*64) into buffer bi: 4 x 1KB wave-loads (2 K + 2 V)
  auto stage = [&](int kt, int bi) {
#pragma unroll
    for (int i = 0; i < 2; ++i) {
      int blk8 = w * 2 + i;
      async_copy16(&kstage[(long)(kt + blk8 * 8 + srow) * D_ + schunk], &Ks[bi][blk8 * 512]);
      async_copy16(&vstage[(long)(blk8 * 8 + srow) * S_ + kt + schunk], &Vs[bi][blk8 * 512]);
    }
  };

  // prologue: mask(0) + stage(0) -> buf 0
  unsigned long long mw_cur0 = mbase[q0];
  unsigned long long mw_cur1 = mbase[q0 + 16];
  stage(0, 0);

  int cur = 0;
  for (int t = 0; t < S_ / 64; ++t) {
    const int kt = t * 64;
    unsigned long long mw_nxt0 = 0, mw_nxt1 = 0;
    if (t < S_ / 64 - 1) {
      // prefetch next tile: 2 mask words + 4 stage loads, then counted wait.
      // "memory" clobbers pin issue order so vmcnt(6) = exactly {mask,stage}(t+1).
      mw_nxt0 = mbase[(((t + 1)) << 11) + q0];
      mw_nxt1 = mbase[(((t + 1)) << 11) + q0 + 16];
      stage(kt + 64, cur ^ 1);
      asm volatile("s_waitcnt vmcnt(6)" ::: "memory");
    } else {
      asm volatile("s_waitcnt vmcnt(0)" ::: "memory");
    }
    __builtin_amdgcn_s_barrier();
    asm volatile("" ::: "memory");

    const unsigned short* Kbuf = &Ks[cur][0];
    const unsigned short* Vbuf = &Vs[cur][0];

    // ---- QK^T (transposed), K frags shared across both q-fragments ----
    f32x4 lt[2][4];
#pragma unroll
    for (int g2 = 0; g2 < 4; ++g2) {
      const unsigned short* kr = &Kbuf[(g2 * 16 + l15) * 64];
      short8v kf0 = *reinterpret_cast<const short8v*>(&kr[(g ^ swz) * 8]);
      short8v kf1 = *reinterpret_cast<const short8v*>(&kr[((g + 4) ^ swz) * 8]);
#pragma unroll
      for (int qf = 0; qf < 2; ++qf) {
        f32x4 c = zero;
        c = __builtin_amdgcn_mfma_f32_16x16x32_bf16(kf0, qfr[qf][0], c, 0, 0, 0);
        c = __builtin_amdgcn_mfma_f32_16x16x32_bf16(kf1, qfr[qf][1], c, 0, 0, 0);
        lt[qf][g2] = c;
      }
    }

    // ---- online softmax per q-fragment, fully in-register ----
    short8v pfr[2][2];
#pragma unroll
    for (int qf = 0; qf < 2; ++qf) {
      unsigned long long mw = qf ? mw_cur1 : mw_cur0;
      float tmax = -1e30f;
#pragma unroll
      for (int g2 = 0; g2 < 4; ++g2)
#pragma unroll
        for (int r = 0; r < 4; ++r) {
          int krel = g2 * 16 + g * 4 + r;  // Lt row = key
          float v = ((mw >> krel) & 1ull) ? -1e30f : lt[qf][g2][r];
          lt[qf][g2][r] = v;
          tmax = fmaxf(tmax, v);
        }
      tmax = fmaxf(tmax, __shfl_xor(tmax, 16));
      tmax = fmaxf(tmax, __shfl_xor(tmax, 32));
      float m_new = fmaxf(m_run[qf], tmax);
      float alpha = __builtin_amdgcn_exp2f(m_run[qf] - m_new);
      float p[4][4];
      float tsum = 0.f;
#pragma unroll
      for (int g2 = 0; g2 < 4; ++g2)
#pragma unroll
        for (int r = 0; r < 4; ++r) {
          p[g2][r] = __builtin_amdgcn_exp2f(lt[qf][g2][r] - m_new);
          tsum += p[g2][r];
        }
      tsum += __shfl_xor(tsum, 16);
      tsum += __shfl_xor(tsum, 32);
      l_run[qf] = l_run[qf] * alpha + tsum;
      m_run[qf] = m_new;
#pragma unroll
      for (int d = 0; d < 4; ++d) oacc[qf][d] *= alpha;
      // pack P^T B-fragment in-register: pfr[s][j] = p[2s + (j>>2)][j&3]
#pragma unroll
      for (int s = 0; s < 2; ++s) {
        union { unsigned u[4]; short8v v; } pu;
        pu.u[0] = cvt_pk_bf16(p[2 * s][0], p[2 * s][1]);
        pu.u[1] = cvt_pk_bf16(p[2 * s][2], p[2 * s][3]);
        pu.u[2] = cvt_pk_bf16(p[2 * s + 1][0], p[2 * s + 1][1]);
        pu.u[3] = cvt_pk_bf16(p[2 * s + 1][2], p[2 * s + 1][3]);
        pfr[qf][s] = pu.v;
      }
    }

    // ---- PV: O^T += V^T * P^T, V frags shared across both q-fragments ----
#pragma unroll
    for (int d0 = 0; d0 < 4; ++d0) {
      const unsigned short* vr = &Vbuf[(d0 * 16 + l15) * 64];
#pragma unroll
      for (int s = 0; s < 2; ++s) {
        short8v vf = *reinterpret_cast<const short8v*>(&vr[((s * 4 + g) ^ swz) * 8]);
#pragma unroll
        for (int qf = 0; qf < 2; ++qf)
          oacc[qf][d0] = __builtin_amdgcn_mfma_f32_16x16x32_bf16(vf, pfr[qf][s], oacc[qf][d0], 0, 0, 0);
      }
    }

    asm volatile("" ::: "memory");
    __builtin_amdgcn_s_barrier();
    asm volatile("" ::: "memory");
    mw_cur0 = mw_nxt0;
    mw_cur1 = mw_nxt1;
    cur ^= 1;
  }

#pragma unroll
  for (int qf = 0; qf < 2; ++qf) {
    float inv = 1.f / l_run[qf];
    int q = q0 + qf * 16;
#pragma unroll
    for (int d0 = 0; d0 < 4; ++d0) {
      ushort4 o;
      o.x = f2bf(oacc[qf][d0][0] * inv);
      o.y = f2bf(oacc[qf][d0][1] * inv);
      o.z = f2bf(oacc[qf][d0][2] * inv);
      o.w = f2bf(oacc[qf][d0][3] * inv);
      *reinterpret_cast<ushort4*>(&attn[((long)b * S_ + q) * D_ + h * HD_ + d0 * 16 + g * 4]) = o;
    }
  }
}

// ---------------- launch ----------------
extern "C" void kernel_launch(void* const* d_in, const int* in_sizes, int n_in,
                              void* d_out, int out_size, void* d_ws, size_t ws_size,
                              hipStream_t stream) {
  const float* query = (const float*)d_in[0];
  const float* key   = (const float*)d_in[1];
  const float* value = (const float*)d_in[2];
  const float* mask  = (const float*)d_in[3];
  const float* Wq = (const float*)d_in[4];
  const float* bq = (const float*)d_in[5];
  const float* Wk = (const float*)d_in[6];
  const float* bk = (const float*)d_in[7];
  const float* Wv = (const float*)d_in[8];
  const float* bv = (const float*)d_in[9];
  const float* Wo = (const float*)d_in[10];
  const float* bo = (const float*)d_in[11];

  char* ws = (char*)d_ws;
  // layout (bytes): XQ 0..16M, XK 16..32M, XV 32..48M, weights 48..56M,
  // QB 56..72M, KB 72..88M, VT 88..104M. attn reuses XQ, mask bits reuse XK.
  unsigned short* XQ  = (unsigned short*)(ws);
  unsigned short* XK  = (unsigned short*)(ws + (16ull << 20));
  unsigned short* XV  = (unsigned short*)(ws + (32ull << 20));
  unsigned short* WQT = (unsigned short*)(ws + (48ull << 20));
  unsigned short* WKT = (unsigned short*)(ws + (50ull << 20));
  unsigned short* WVT = (unsigned short*)(ws + (52ull << 20));
  unsigned short* WOT = (unsigned short*)(ws + (54ull << 20));
  unsigned short* QB  = (unsigned short*)(ws + (56ull << 20));
  unsigned short* KB  = (unsigned short*)(ws + (72ull << 20));
  unsigned short* VT  = (unsigned short*)(ws + (88ull << 20));
  unsigned long long* MBITS = (unsigned long long*)(ws + (16ull << 20));
  unsigned short* ATTN = XQ;

  const int n4 = M_ * D_ / 4;
  cast_bf16_kernel<<<2048, 256, 0, stream>>>(query, XQ, n4);
  cast_bf16_kernel<<<2048, 256, 0, stream>>>(key,   XK, n4);
  cast_bf16_kernel<<<2048, 256, 0, stream>>>(value, XV, n4);

  dim3 tg(D_ / 32, D_ / 32), tb(32, 8);
  transpose_cast_kernel<<<tg, tb, 0, stream>>>(Wq, WQT, D_);
  transpose_cast_kernel<<<tg, tb, 0, stream>>>(Wk, WKT, D_);
  transpose_cast_kernel<<<tg, tb, 0, stream>>>(Wv, WVT, D_);
  transpose_cast_kernel<<<tg, tb, 0, stream>>>(Wo, WOT, D_);

  dim3 gg(M_ / 128, D_ / 128);
  // Q prescale: 1/sqrt(HD) * log2(e) so softmax runs in exp2 domain
  gemm_bt_kernel<0><<<gg, 256, 0, stream>>>(XQ, WQT, bq, QB, M_, D_, D_, 0.18033688011112042f);
  gemm_bt_kernel<0><<<gg, 256, 0, stream>>>(XK, WKT, bk, KB, M_, D_, D_, 1.f);
  gemm_bt_kernel<1><<<gg, 256, 0, stream>>>(XV, WVT, bv, VT, M_, D_, D_, 1.f);

  pack_mask_kernel<<<2048, 256, 0, stream>>>(mask, MBITS, B_ * S_ * S_ / 64);

  dim3 ag(S_ / 128, B_ * H_);
  attn_kernel<<<ag, 256, 0, stream>>>(QB, KB, VT, MBITS, ATTN);

  gemm_bt_kernel<2><<<gg, 256, 0, stream>>>(ATTN, WOT, bo, d_out, M_, D_, D_, 1.f);
}

// Round 9
// 309.704 us; speedup vs baseline: 1.0269x; 1.0269x over previous
//
#include <hip/hip_runtime.h>

#define DI __device__ __forceinline__

typedef __attribute__((ext_vector_type(8))) short short8v;
typedef __attribute__((ext_vector_type(4))) float f32x4;

static constexpr int B_ = 4, S_ = 2048, D_ = 1024, H_ = 16, HD_ = 64;
static constexpr int M_ = B_ * S_;  // 8192 rows

// f32 -> bf16 round-nearest-even
DI unsigned short f2bf(float f) {
  unsigned u = __builtin_bit_cast(unsigned, f);
  u = (u + 0x7fffu + ((u >> 16) & 1u)) >> 16;
  return (unsigned short)u;
}

DI unsigned cvt_pk_bf16(float lo, float hi) {
  unsigned r;
  asm("v_cvt_pk_bf16_f32 %0, %1, %2" : "=v"(r) : "v"(lo), "v"(hi));
  return r;
}

// async global->LDS, 16B per lane; LDS dest must be wave-uniform base (HW adds lane*16)
DI void async_copy16(const void* g, void* l) {
  __builtin_amdgcn_global_load_lds((const __attribute__((address_space(1))) void*)g,
                                   (__attribute__((address_space(3))) void*)l, 16, 0, 0);
}

// ---------------- elementwise cast f32 -> bf16 (vectorized) ----------------
__global__ __launch_bounds__(256) void cast_bf16_kernel(const float* __restrict__ in,
                                                        unsigned short* __restrict__ out,
                                                        int n4) {
  int i = blockIdx.x * blockDim.x + threadIdx.x;
  int stride = gridDim.x * blockDim.x;
  for (; i < n4; i += stride) {
    float4 v = reinterpret_cast<const float4*>(in)[i];
    ushort4 o;
    o.x = f2bf(v.x); o.y = f2bf(v.y); o.z = f2bf(v.z); o.w = f2bf(v.w);
    reinterpret_cast<ushort4*>(out)[i] = o;
  }
}

// ---------------- transpose + cast weights: W[K,N] f32 -> Wt[N,K] bf16 ----------------
__global__ __launch_bounds__(256) void transpose_cast_kernel(const float* __restrict__ W,
                                                             unsigned short* __restrict__ Wt,
                                                             int n) {
  __shared__ float t[32][33];
  int bx = blockIdx.x * 32, by = blockIdx.y * 32;
  int x = threadIdx.x, y0 = threadIdx.y;
#pragma unroll
  for (int yy = 0; yy < 32; yy += 8)
    t[y0 + yy][x] = W[(long)(by + y0 + yy) * n + bx + x];
  __syncthreads();
#pragma unroll
  for (int yy = 0; yy < 32; yy += 8)
    Wt[(long)(bx + y0 + yy) * n + by + x] = f2bf(t[x][y0 + yy]);
}

// ---------------- pack mask (0/1 f32) into bit words, layout [B][S/64 kt][S q] ----------------
__global__ __launch_bounds__(256) void pack_mask_kernel(const float* __restrict__ mask,
                                                        unsigned long long* __restrict__ bits,
                                                        int nwords) {
  int lane = threadIdx.x & 63;
  int wpb = blockDim.x >> 6;
  int w = blockIdx.x * wpb + (threadIdx.x >> 6);
  int stride = gridDim.x * wpb;
  for (; w < nwords; w += stride) {
    float v = mask[(long)w * 64 + lane];
    unsigned long long b = __ballot(v > 0.5f);
    if (lane == 0) {
      int bb = w >> 16, q = (w >> 5) & 2047, kt64 = w & 31;
      bits[((long)bb << 16) | (kt64 << 11) | q] = b;
    }
  }
}

// ---------------- GEMM: C[M,N] = A[M,K] * Bt[N,K]^T + bias, bf16 MFMA ----------------
// v2: double-buffered LDS, 2-phase pipeline (stage t+1 before compute t, one barrier/tile),
// sched_barrier(0) after each inline waitcnt (rule-18 hardening).
// MODE 0: bf16 out [M,N], val=(acc+bias)*scale
// MODE 1: bf16 out as per-head transposed V with key-permuted columns (see round-3 note)
// MODE 2: f32 out [M,N]
template <int MODE>
__global__ __launch_bounds__(256) void gemm_bt_kernel(const unsigned short* __restrict__ A,
                                                      const unsigned short* __restrict__ Bt,
                                                      const float* __restrict__ bias,
                                                      void* __restrict__ out,
                                                      int Mdim, int Ndim, int Kdim, float scale) {
  __shared__ unsigned short As[2][128 * 32];
  __shared__ unsigned short Bs[2][128 * 32];
  const int tid = threadIdx.x;
  const int lane = tid & 63;
  const int w = tid >> 6;
  const int g = lane >> 4;
  const int l15 = lane & 15;
  const int bm = blockIdx.x * 128;
  const int bn = blockIdx.y * 128;
  const int wr = w >> 1, wc = w & 1;

  f32x4 zero = {0.f, 0.f, 0.f, 0.f};
  f32x4 acc[4][4];
#pragma unroll
  for (int i = 0; i < 4; ++i)
#pragma unroll
    for (int j = 0; j < 4; ++j) acc[i][j] = zero;

  const int srow = lane >> 2;        // 0..15 within 16-row chunk
  const int scol = (lane & 3) * 8;   // bf16 col offset, 8 elems = 16B

  auto stageg = [&](int k0, int bi) {
#pragma unroll
    for (int i = 0; i < 2; ++i) {
      int q = w * 2 + i;             // 1KB chunk index, rows [q*16, q*16+16)
      int row = q * 16 + srow;
      async_copy16(&A[(long)(bm + row) * Kdim + k0 + scol], &As[bi][q * 512]);
      async_copy16(&Bt[(long)(bn + row) * Kdim + k0 + scol], &Bs[bi][q * 512]);
    }
  };

  // prologue: stage tile 0, drain, barrier
  stageg(0, 0);
  asm volatile("s_waitcnt vmcnt(0)" ::: "memory");
  __builtin_amdgcn_sched_barrier(0);
  __builtin_amdgcn_s_barrier();
  asm volatile("" ::: "memory");

  const int NT = Kdim / 32;
  int cur = 0;
  for (int t = 0; t < NT; ++t) {
    // issue next-tile staging first; its HBM/L2 latency hides under this tile's compute
    if (t + 1 < NT) stageg((t + 1) * 32, cur ^ 1);

    short8v a[4], b[4];
#pragma unroll
    for (int i = 0; i < 4; ++i)
      a[i] = *reinterpret_cast<const short8v*>(&As[cur][(wr * 64 + i * 16 + l15) * 32 + g * 8]);
#pragma unroll
    for (int j = 0; j < 4; ++j)
      b[j] = *reinterpret_cast<const short8v*>(&Bs[cur][(wc * 64 + j * 16 + l15) * 32 + g * 8]);
#pragma unroll
    for (int i = 0; i < 4; ++i)
#pragma unroll
      for (int j = 0; j < 4; ++j)
        acc[i][j] = __builtin_amdgcn_mfma_f32_16x16x32_bf16(a[i], b[j], acc[i][j], 0, 0, 0);

    // stage(t+1) landed + this tile's ds_reads done, then single barrier per tile
    asm volatile("s_waitcnt vmcnt(0) lgkmcnt(0)" ::: "memory");
    __builtin_amdgcn_sched_barrier(0);
    __builtin_amdgcn_s_barrier();
    asm volatile("" ::: "memory");
    cur ^= 1;
  }

#pragma unroll
  for (int jj = 0; jj < 4; ++jj) {
    int n = bn + wc * 64 + jj * 16 + l15;
    float bs = bias[n];
#pragma unroll
    for (int i = 0; i < 4; ++i) {
      int m0 = bm + wr * 64 + i * 16 + g * 4;  // rows m0..m0+3 (reg r)
      if (MODE == 0) {
        unsigned short* o = (unsigned short*)out;
#pragma unroll
        for (int r = 0; r < 4; ++r)
          o[(long)(m0 + r) * Ndim + n] = f2bf((acc[i][jj][r] + bs) * scale);
      } else if (MODE == 1) {
        int b2 = m0 >> 11, s0 = m0 & 2047;
        int s0p = (s0 & ~31) | (((s0 >> 2) & 3) << 3) | (((s0 >> 4) & 1) << 2);
        int h2 = n >> 6, d2 = n & 63;
        unsigned short* o = (unsigned short*)out;
        ushort4 v;
        v.x = f2bf(acc[i][jj][0] + bs);
        v.y = f2bf(acc[i][jj][1] + bs);
        v.z = f2bf(acc[i][jj][2] + bs);
        v.w = f2bf(acc[i][jj][3] + bs);
        *reinterpret_cast<ushort4*>(&o[((long)((b2 * 16 + h2) * 64 + d2) << 11) + s0p]) = v;
      } else {
        float* o = (float*)out;
#pragma unroll
        for (int r = 0; r < 4; ++r)
          o[(long)(m0 + r) * Ndim + n] = acc[i][jj][r] + bs;
      }
    }
  }
}

// ---------------- fused flash attention (VERBATIM round-4: passed at 146us) ----------------
__global__ __launch_bounds__(256, 2) void attn_kernel(const unsigned short* __restrict__ Q,   // [B,S,D] pre-scaled log2e/8
                                                      const unsigned short* __restrict__ Kb,  // [B,S,D]
                                                      const unsigned short* __restrict__ Vt,  // [B*H,64,S] key-permuted
                                                      const unsigned long long* __restrict__ mbits, // [B][32][2048]
                                                      unsigned short* __restrict__ attn) {    // [B,S,D]
  __shared__ unsigned short Ks[2][64 * 64];       // swizzled, rows = key
  __shared__ unsigned short Vs[2][64 * 64];       // swizzled, rows = d
  const int lane = threadIdx.x & 63;
  const int w = threadIdx.x >> 6;
  const int g = lane >> 4;
  const int l15 = lane & 15;
  const int qt = blockIdx.x;
  const int bh = blockIdx.y;
  const int b = bh >> 4, h = bh & 15;
  const int q0 = qt * 128 + w * 32 + l15;  // qf=0 row; qf=1 row = q0+16

  // Q fragments double as MFMA B-operand: col n=q=lane&15, k=d=g*8+j (+32)
  const unsigned short* qp = Q + ((long)b * S_ + q0) * D_ + h * HD_ + g * 8;
  short8v qfr[2][2];
  qfr[0][0] = *reinterpret_cast<const short8v*>(qp);
  qfr[0][1] = *reinterpret_cast<const short8v*>(qp + 32);
  qfr[1][0] = *reinterpret_cast<const short8v*>(qp + 16 * D_);
  qfr[1][1] = *reinterpret_cast<const short8v*>(qp + 16 * D_ + 32);

  // staging: LDS chunk c holds global chunk c ^ (row&7)  (inverse-swizzled source)
  const int srow = lane >> 3;
  const int schunk = ((lane & 7) ^ (lane >> 3)) * 8;  // in elements
  const unsigned short* kstage = Kb + (long)b * S_ * D_ + h * HD_;
  const unsigned short* vstage = Vt + (long)bh * HD_ * S_;

  f32x4 zero = {0.f, 0.f, 0.f, 0.f};
  f32x4 oacc[2][4];
#pragma unroll
  for (int qf = 0; qf < 2; ++qf)
#pragma unroll
    for (int d = 0; d < 4; ++d) oacc[qf][d] = zero;
  float m_run[2] = {-1e30f, -1e30f}, l_run[2] = {0.f, 0.f};

  const unsigned long long* mbase = mbits + ((long)b << 16);
  const int swz = l15 & 7;

  auto stage = [&](int kt, int bi) {
#pragma unroll
    for (int i = 0; i < 2; ++i) {
      int blk8 = w * 2 + i;
      async_copy16(&kstage[(long)(kt + blk8 * 8 + srow) * D_ + schunk], &Ks[bi][blk8 * 512]);
      async_copy16(&vstage[(long)(blk8 * 8 + srow) * S_ + kt + schunk], &Vs[bi][blk8 * 512]);
    }
  };

  // prologue: mask(0) + stage(0) -> buf 0
  unsigned long long mw_cur0 = mbase[q0];
  unsigned long long mw_cur1 = mbase[q0 + 16];
  stage(0, 0);

  int cur = 0;
  for (int t = 0; t < S_ / 64; ++t) {
    unsigned long long mw_nxt0 = 0, mw_nxt1 = 0;
    if (t < S_ / 64 - 1) {
      // prefetch next tile: 2 mask words + 4 stage loads, then counted wait.
      mw_nxt0 = mbase[((t + 1) << 11) + q0];
      mw_nxt1 = mbase[((t + 1) << 11) + q0 + 16];
      stage((t + 1) * 64, cur ^ 1);
      asm volatile("s_waitcnt vmcnt(6)" ::: "memory");
    } else {
      asm volatile("s_waitcnt vmcnt(0)" ::: "memory");
    }
    __builtin_amdgcn_s_barrier();
    asm volatile("" ::: "memory");

    const unsigned short* Kbuf = &Ks[cur][0];
    const unsigned short* Vbuf = &Vs[cur][0];

    // ---- QK^T (transposed), K frags shared across both q-fragments ----
    f32x4 lt[2][4];
#pragma unroll
    for (int g2 = 0; g2 < 4; ++g2) {
      const unsigned short* kr = &Kbuf[(g2 * 16 + l15) * 64];
      short8v kf0 = *reinterpret_cast<const short8v*>(&kr[(g ^ swz) * 8]);
      short8v kf1 = *reinterpret_cast<const short8v*>(&kr[((g + 4) ^ swz) * 8]);
#pragma unroll
      for (int qf = 0; qf < 2; ++qf) {
        f32x4 c = zero;
        c = __builtin_amdgcn_mfma_f32_16x16x32_bf16(kf0, qfr[qf][0], c, 0, 0, 0);
        c = __builtin_amdgcn_mfma_f32_16x16x32_bf16(kf1, qfr[qf][1], c, 0, 0, 0);
        lt[qf][g2] = c;
      }
    }

    // ---- online softmax per q-fragment, fully in-register ----
    short8v pfr[2][2];
#pragma unroll
    for (int qf = 0; qf < 2; ++qf) {
      unsigned long long mw = qf ? mw_cur1 : mw_cur0;
      float tmax = -1e30f;
#pragma unroll
      for (int g2 = 0; g2 < 4; ++g2)
#pragma unroll
        for (int r = 0; r < 4; ++r) {
          int krel = g2 * 16 + g * 4 + r;  // Lt row = key
          float v = ((mw >> krel) & 1ull) ? -1e30f : lt[qf][g2][r];
          lt[qf][g2][r] = v;
          tmax = fmaxf(tmax, v);
        }
      tmax = fmaxf(tmax, __shfl_xor(tmax, 16));
      tmax = fmaxf(tmax, __shfl_xor(tmax, 32));
      float m_new = fmaxf(m_run[qf], tmax);
      float alpha = __builtin_amdgcn_exp2f(m_run[qf] - m_new);
      float p[4][4];
      float tsum = 0.f;
#pragma unroll
      for (int g2 = 0; g2 < 4; ++g2)
#pragma unroll
        for (int r = 0; r < 4; ++r) {
          p[g2][r] = __builtin_amdgcn_exp2f(lt[qf][g2][r] - m_new);
          tsum += p[g2][r];
        }
      tsum += __shfl_xor(tsum, 16);
      tsum += __shfl_xor(tsum, 32);
      l_run[qf] = l_run[qf] * alpha + tsum;
      m_run[qf] = m_new;
#pragma unroll
      for (int d = 0; d < 4; ++d) oacc[qf][d] *= alpha;
      // pack P^T B-fragment in-register: pfr[s][j] = p[2s + (j>>2)][j&3]
#pragma unroll
      for (int s = 0; s < 2; ++s) {
        union { unsigned u[4]; short8v v; } pu;
        pu.u[0] = cvt_pk_bf16(p[2 * s][0], p[2 * s][1]);
        pu.u[1] = cvt_pk_bf16(p[2 * s][2], p[2 * s][3]);
        pu.u[2] = cvt_pk_bf16(p[2 * s + 1][0], p[2 * s + 1][1]);
        pu.u[3] = cvt_pk_bf16(p[2 * s + 1][2], p[2 * s + 1][3]);
        pfr[qf][s] = pu.v;
      }
    }

    // ---- PV: O^T += V^T * P^T, V frags shared across both q-fragments ----
#pragma unroll
    for (int d0 = 0; d0 < 4; ++d0) {
      const unsigned short* vr = &Vbuf[(d0 * 16 + l15) * 64];
#pragma unroll
      for (int s = 0; s < 2; ++s) {
        short8v vf = *reinterpret_cast<const short8v*>(&vr[((s * 4 + g) ^ swz) * 8]);
#pragma unroll
        for (int qf = 0; qf < 2; ++qf)
          oacc[qf][d0] = __builtin_amdgcn_mfma_f32_16x16x32_bf16(vf, pfr[qf][s], oacc[qf][d0], 0, 0, 0);
      }
    }

    asm volatile("" ::: "memory");
    __builtin_amdgcn_s_barrier();
    asm volatile("" ::: "memory");
    mw_cur0 = mw_nxt0;
    mw_cur1 = mw_nxt1;
    cur ^= 1;
  }

#pragma unroll
  for (int qf = 0; qf < 2; ++qf) {
    float inv = 1.f / l_run[qf];
    int q = q0 + qf * 16;
#pragma unroll
    for (int d0 = 0; d0 < 4; ++d0) {
      ushort4 o;
      o.x = f2bf(oacc[qf][d0][0] * inv);
      o.y = f2bf(oacc[qf][d0][1] * inv);
      o.z = f2bf(oacc[qf][d0][2] * inv);
      o.w = f2bf(oacc[qf][d0][3] * inv);
      *reinterpret_cast<ushort4*>(&attn[((long)b * S_ + q) * D_ + h * HD_ + d0 * 16 + g * 4]) = o;
    }
  }
}

// ---------------- launch ----------------
extern "C" void kernel_launch(void* const* d_in, const int* in_sizes, int n_in,
                              void* d_out, int out_size, void* d_ws, size_t ws_size,
                              hipStream_t stream) {
  const float* query = (const float*)d_in[0];
  const float* key   = (const float*)d_in[1];
  const float* value = (const float*)d_in[2];
  const float* mask  = (const float*)d_in[3];
  const float* Wq = (const float*)d_in[4];
  const float* bq = (const float*)d_in[5];
  const float* Wk = (const float*)d_in[6];
  const float* bk = (const float*)d_in[7];
  const float* Wv = (const float*)d_in[8];
  const float* bv = (const float*)d_in[9];
  const float* Wo = (const float*)d_in[10];
  const float* bo = (const float*)d_in[11];

  char* ws = (char*)d_ws;
  unsigned short* XQ  = (unsigned short*)(ws);
  unsigned short* XK  = (unsigned short*)(ws + (16ull << 20));
  unsigned short* XV  = (unsigned short*)(ws + (32ull << 20));
  unsigned short* WQT = (unsigned short*)(ws + (48ull << 20));
  unsigned short* WKT = (unsigned short*)(ws + (50ull << 20));
  unsigned short* WVT = (unsigned short*)(ws + (52ull << 20));
  unsigned short* WOT = (unsigned short*)(ws + (54ull << 20));
  unsigned short* QB  = (unsigned short*)(ws + (56ull << 20));
  unsigned short* KB  = (unsigned short*)(ws + (72ull << 20));
  unsigned short* VT  = (unsigned short*)(ws + (88ull << 20));
  unsigned long long* MBITS = (unsigned long long*)(ws + (16ull << 20));
  unsigned short* ATTN = XQ;

  const int n4 = M_ * D_ / 4;
  cast_bf16_kernel<<<2048, 256, 0, stream>>>(query, XQ, n4);
  cast_bf16_kernel<<<2048, 256, 0, stream>>>(key,   XK, n4);
  cast_bf16_kernel<<<2048, 256, 0, stream>>>(value, XV, n4);

  dim3 tg(D_ / 32, D_ / 32), tb(32, 8);
  transpose_cast_kernel<<<tg, tb, 0, stream>>>(Wq, WQT, D_);
  transpose_cast_kernel<<<tg, tb, 0, stream>>>(Wk, WKT, D_);
  transpose_cast_kernel<<<tg, tb, 0, stream>>>(Wv, WVT, D_);
  transpose_cast_kernel<<<tg, tb, 0, stream>>>(Wo, WOT, D_);

  dim3 gg(M_ / 128, D_ / 128);
  // Q prescale: 1/sqrt(HD) * log2(e) so softmax runs in exp2 domain
  gemm_bt_kernel<0><<<gg, 256, 0, stream>>>(XQ, WQT, bq, QB, M_, D_, D_, 0.18033688011112042f);
  gemm_bt_kernel<0><<<gg, 256, 0, stream>>>(XK, WKT, bk, KB, M_, D_, D_, 1.f);
  gemm_bt_kernel<1><<<gg, 256, 0, stream>>>(XV, WVT, bv, VT, M_, D_, D_, 1.f);

  pack_mask_kernel<<<2048, 256, 0, stream>>>(mask, MBITS, B_ * S_ * S_ / 64);

  dim3 ag(S_ / 128, B_ * H_);
  attn_kernel<<<ag, 256, 0, stream>>>(QB, KB, VT, MBITS, ATTN);

  gemm_bt_kernel<2><<<gg, 256, 0, stream>>>(ATTN, WOT, bo, d_out, M_, D_, D_, 1.f);
}

// Round 10
// 308.302 us; speedup vs baseline: 1.0316x; 1.0045x over previous
//
#include <hip/hip_runtime.h>

#define DI __device__ __forceinline__

typedef __attribute__((ext_vector_type(8))) short short8v;
typedef __attribute__((ext_vector_type(4))) float f32x4;

static constexpr int B_ = 4, S_ = 2048, D_ = 1024, H_ = 16, HD_ = 64;
static constexpr int M_ = B_ * S_;  // 8192 rows

// f32 -> bf16 round-nearest-even
DI unsigned short f2bf(float f) {
  unsigned u = __builtin_bit_cast(unsigned, f);
  u = (u + 0x7fffu + ((u >> 16) & 1u)) >> 16;
  return (unsigned short)u;
}

DI unsigned cvt_pk_bf16(float lo, float hi) {
  unsigned r;
  asm("v_cvt_pk_bf16_f32 %0, %1, %2" : "=v"(r) : "v"(lo), "v"(hi));
  return r;
}

// async global->LDS, 16B per lane; LDS dest must be wave-uniform base (HW adds lane*16)
DI void async_copy16(const void* g, void* l) {
  __builtin_amdgcn_global_load_lds((const __attribute__((address_space(1))) void*)g,
                                   (__attribute__((address_space(3))) void*)l, 16, 0, 0);
}

// ---------------- elementwise cast f32 -> bf16 (vectorized) ----------------
__global__ __launch_bounds__(256) void cast_bf16_kernel(const float* __restrict__ in,
                                                        unsigned short* __restrict__ out,
                                                        int n4) {
  int i = blockIdx.x * blockDim.x + threadIdx.x;
  int stride = gridDim.x * blockDim.x;
  for (; i < n4; i += stride) {
    float4 v = reinterpret_cast<const float4*>(in)[i];
    ushort4 o;
    o.x = f2bf(v.x); o.y = f2bf(v.y); o.z = f2bf(v.z); o.w = f2bf(v.w);
    reinterpret_cast<ushort4*>(out)[i] = o;
  }
}

// ---------------- transpose + cast weights: W[K,N] f32 -> Wt[N,K] bf16 ----------------
__global__ __launch_bounds__(256) void transpose_cast_kernel(const float* __restrict__ W,
                                                             unsigned short* __restrict__ Wt,
                                                             int n) {
  __shared__ float t[32][33];
  int bx = blockIdx.x * 32, by = blockIdx.y * 32;
  int x = threadIdx.x, y0 = threadIdx.y;
#pragma unroll
  for (int yy = 0; yy < 32; yy += 8)
    t[y0 + yy][x] = W[(long)(by + y0 + yy) * n + bx + x];
  __syncthreads();
#pragma unroll
  for (int yy = 0; yy < 32; yy += 8)
    Wt[(long)(bx + y0 + yy) * n + by + x] = f2bf(t[x][y0 + yy]);
}

// ---------------- pack mask (0/1 f32) into bit words, layout [B][S/64 kt][S q] ----------------
__global__ __launch_bounds__(256) void pack_mask_kernel(const float* __restrict__ mask,
                                                        unsigned long long* __restrict__ bits,
                                                        int nwords) {
  int lane = threadIdx.x & 63;
  int wpb = blockDim.x >> 6;
  int w = blockIdx.x * wpb + (threadIdx.x >> 6);
  int stride = gridDim.x * wpb;
  for (; w < nwords; w += stride) {
    float v = mask[(long)w * 64 + lane];
    unsigned long long b = __ballot(v > 0.5f);
    if (lane == 0) {
      int bb = w >> 16, q = (w >> 5) & 2047, kt64 = w & 31;
      bits[((long)bb << 16) | (kt64 << 11) | q] = b;
    }
  }
}

// ---------------- GEMM: C[M,N] = A[M,K] * Bt[N,K]^T + bias, bf16 MFMA ----------------
// v2 (round-9, PASSED): double-buffered LDS, 2-phase pipeline, sched_barrier hardening.
// MODE 0: bf16 out [M,N], val=(acc+bias)*scale
// MODE 1: bf16 out as per-head transposed V with key-permuted columns (see round-3 note)
// MODE 2: f32 out [M,N]
template <int MODE>
__global__ __launch_bounds__(256) void gemm_bt_kernel(const unsigned short* __restrict__ A,
                                                      const unsigned short* __restrict__ Bt,
                                                      const float* __restrict__ bias,
                                                      void* __restrict__ out,
                                                      int Mdim, int Ndim, int Kdim, float scale) {
  __shared__ unsigned short As[2][128 * 32];
  __shared__ unsigned short Bs[2][128 * 32];
  const int tid = threadIdx.x;
  const int lane = tid & 63;
  const int w = tid >> 6;
  const int g = lane >> 4;
  const int l15 = lane & 15;
  const int bm = blockIdx.x * 128;
  const int bn = blockIdx.y * 128;
  const int wr = w >> 1, wc = w & 1;

  f32x4 zero = {0.f, 0.f, 0.f, 0.f};
  f32x4 acc[4][4];
#pragma unroll
  for (int i = 0; i < 4; ++i)
#pragma unroll
    for (int j = 0; j < 4; ++j) acc[i][j] = zero;

  const int srow = lane >> 2;        // 0..15 within 16-row chunk
  const int scol = (lane & 3) * 8;   // bf16 col offset, 8 elems = 16B

  auto stageg = [&](int k0, int bi) {
#pragma unroll
    for (int i = 0; i < 2; ++i) {
      int q = w * 2 + i;             // 1KB chunk index, rows [q*16, q*16+16)
      int row = q * 16 + srow;
      async_copy16(&A[(long)(bm + row) * Kdim + k0 + scol], &As[bi][q * 512]);
      async_copy16(&Bt[(long)(bn + row) * Kdim + k0 + scol], &Bs[bi][q * 512]);
    }
  };

  // prologue: stage tile 0, drain, barrier
  stageg(0, 0);
  asm volatile("s_waitcnt vmcnt(0)" ::: "memory");
  __builtin_amdgcn_sched_barrier(0);
  __builtin_amdgcn_s_barrier();
  asm volatile("" ::: "memory");

  const int NT = Kdim / 32;
  int cur = 0;
  for (int t = 0; t < NT; ++t) {
    // issue next-tile staging first; its HBM/L2 latency hides under this tile's compute
    if (t + 1 < NT) stageg((t + 1) * 32, cur ^ 1);

    short8v a[4], b[4];
#pragma unroll
    for (int i = 0; i < 4; ++i)
      a[i] = *reinterpret_cast<const short8v*>(&As[cur][(wr * 64 + i * 16 + l15) * 32 + g * 8]);
#pragma unroll
    for (int j = 0; j < 4; ++j)
      b[j] = *reinterpret_cast<const short8v*>(&Bs[cur][(wc * 64 + j * 16 + l15) * 32 + g * 8]);
#pragma unroll
    for (int i = 0; i < 4; ++i)
#pragma unroll
      for (int j = 0; j < 4; ++j)
        acc[i][j] = __builtin_amdgcn_mfma_f32_16x16x32_bf16(a[i], b[j], acc[i][j], 0, 0, 0);

    // stage(t+1) landed + this tile's ds_reads done, then single barrier per tile
    asm volatile("s_waitcnt vmcnt(0) lgkmcnt(0)" ::: "memory");
    __builtin_amdgcn_sched_barrier(0);
    __builtin_amdgcn_s_barrier();
    asm volatile("" ::: "memory");
    cur ^= 1;
  }

#pragma unroll
  for (int jj = 0; jj < 4; ++jj) {
    int n = bn + wc * 64 + jj * 16 + l15;
    float bs = bias[n];
#pragma unroll
    for (int i = 0; i < 4; ++i) {
      int m0 = bm + wr * 64 + i * 16 + g * 4;  // rows m0..m0+3 (reg r)
      if (MODE == 0) {
        unsigned short* o = (unsigned short*)out;
#pragma unroll
        for (int r = 0; r < 4; ++r)
          o[(long)(m0 + r) * Ndim + n] = f2bf((acc[i][jj][r] + bs) * scale);
      } else if (MODE == 1) {
        int b2 = m0 >> 11, s0 = m0 & 2047;
        int s0p = (s0 & ~31) | (((s0 >> 2) & 3) << 3) | (((s0 >> 4) & 1) << 2);
        int h2 = n >> 6, d2 = n & 63;
        unsigned short* o = (unsigned short*)out;
        ushort4 v;
        v.x = f2bf(acc[i][jj][0] + bs);
        v.y = f2bf(acc[i][jj][1] + bs);
        v.z = f2bf(acc[i][jj][2] + bs);
        v.w = f2bf(acc[i][jj][3] + bs);
        *reinterpret_cast<ushort4*>(&o[((long)((b2 * 16 + h2) * 64 + d2) << 11) + s0p]) = v;
      } else {
        float* o = (float*)out;
#pragma unroll
        for (int r = 0; r < 4; ++r)
          o[(long)(m0 + r) * Ndim + n] = acc[i][jj][r] + bs;
      }
    }
  }
}

// ---------------- fused flash attention (v9: round-4 softmax verbatim, QBLK=64) ----------------
// Re-tiling of the PASSING round-4 kernel: each wave owns ONE 16-q fragment (was 2), block
// covers 64 q rows, grid (S/64, B*H) = 2048 blocks. Halves per-wave register state
// (lt/oacc/qfr/pfr) to fix AGPR-bounce/occupancy; softmax semantics byte-identical.
// setprio(1) around MFMA clusters (T5, value-free scheduler hint).
// Counted prefetch: 1 mask + 4 stage loads in flight -> vmcnt(5).
__global__ __launch_bounds__(256, 4) void attn_kernel(const unsigned short* __restrict__ Q,   // [B,S,D] pre-scaled log2e/8
                                                      const unsigned short* __restrict__ Kb,  // [B,S,D]
                                                      const unsigned short* __restrict__ Vt,  // [B*H,64,S] key-permuted
                                                      const unsigned long long* __restrict__ mbits, // [B][32][2048]
                                                      unsigned short* __restrict__ attn) {    // [B,S,D]
  __shared__ unsigned short Ks[2][64 * 64];       // swizzled, rows = key
  __shared__ unsigned short Vs[2][64 * 64];       // swizzled, rows = d
  const int lane = threadIdx.x & 63;
  const int w = threadIdx.x >> 6;
  const int g = lane >> 4;
  const int l15 = lane & 15;
  const int qt = blockIdx.x;
  const int bh = blockIdx.y;
  const int b = bh >> 4, h = bh & 15;
  const int q0 = qt * 64 + w * 16 + l15;  // this wave's q row

  // Q fragment doubles as MFMA B-operand: col n=q=lane&15, k=d=g*8+j (+32)
  const unsigned short* qp = Q + ((long)b * S_ + q0) * D_ + h * HD_ + g * 8;
  short8v qf0 = *reinterpret_cast<const short8v*>(qp);
  short8v qf1 = *reinterpret_cast<const short8v*>(qp + 32);

  // staging: LDS chunk c holds global chunk c ^ (row&7)  (inverse-swizzled source)
  const int srow = lane >> 3;
  const int schunk = ((lane & 7) ^ (lane >> 3)) * 8;  // in elements
  const unsigned short* kstage = Kb + (long)b * S_ * D_ + h * HD_;
  const unsigned short* vstage = Vt + (long)bh * HD_ * S_;

  f32x4 zero = {0.f, 0.f, 0.f, 0.f};
  f32x4 oacc[4] = {zero, zero, zero, zero};
  float m_run = -1e30f, l_run = 0.f;

  const unsigned long long* mbase = mbits + ((long)b << 16);
  const int swz = l15 & 7;

  auto stage = [&](int kt, int bi) {
#pragma unroll
    for (int i = 0; i < 2; ++i) {
      int blk8 = w * 2 + i;
      async_copy16(&kstage[(long)(kt + blk8 * 8 + srow) * D_ + schunk], &Ks[bi][blk8 * 512]);
      async_copy16(&vstage[(long)(blk8 * 8 + srow) * S_ + kt + schunk], &Vs[bi][blk8 * 512]);
    }
  };

  // prologue: mask(0) + stage(0) -> buf 0
  unsigned long long mw_cur = mbase[q0];
  stage(0, 0);

  int cur = 0;
  for (int t = 0; t < S_ / 64; ++t) {
    unsigned long long mw_nxt = 0;
    if (t < S_ / 64 - 1) {
      // prefetch next tile: 1 mask word + 4 stage loads, then counted wait.
      mw_nxt = mbase[((t + 1) << 11) + q0];
      stage((t + 1) * 64, cur ^ 1);
      asm volatile("s_waitcnt vmcnt(5)" ::: "memory");
    } else {
      asm volatile("s_waitcnt vmcnt(0)" ::: "memory");
    }
    __builtin_amdgcn_s_barrier();
    asm volatile("" ::: "memory");

    const unsigned short* Kbuf = &Ks[cur][0];
    const unsigned short* Vbuf = &Vs[cur][0];

    // ---- QK^T (transposed): acc col = q = lane&15, row = key ----
    f32x4 lt[4];
    __builtin_amdgcn_s_setprio(1);
#pragma unroll
    for (int g2 = 0; g2 < 4; ++g2) {
      const unsigned short* kr = &Kbuf[(g2 * 16 + l15) * 64];
      short8v kf0 = *reinterpret_cast<const short8v*>(&kr[(g ^ swz) * 8]);
      short8v kf1 = *reinterpret_cast<const short8v*>(&kr[((g + 4) ^ swz) * 8]);
      f32x4 c = zero;
      c = __builtin_amdgcn_mfma_f32_16x16x32_bf16(kf0, qf0, c, 0, 0, 0);
      c = __builtin_amdgcn_mfma_f32_16x16x32_bf16(kf1, qf1, c, 0, 0, 0);
      lt[g2] = c;
    }
    __builtin_amdgcn_s_setprio(0);

    // ---- online softmax (round-4 verbatim: -1e30 inject, shuffle reductions) ----
    float tmax = -1e30f;
#pragma unroll
    for (int g2 = 0; g2 < 4; ++g2)
#pragma unroll
      for (int r = 0; r < 4; ++r) {
        int krel = g2 * 16 + g * 4 + r;  // Lt row = key
        float v = ((mw_cur >> krel) & 1ull) ? -1e30f : lt[g2][r];
        lt[g2][r] = v;
        tmax = fmaxf(tmax, v);
      }
    tmax = fmaxf(tmax, __shfl_xor(tmax, 16));
    tmax = fmaxf(tmax, __shfl_xor(tmax, 32));
    float m_new = fmaxf(m_run, tmax);
    float alpha = __builtin_amdgcn_exp2f(m_run - m_new);
    float p[4][4];
    float tsum = 0.f;
#pragma unroll
    for (int g2 = 0; g2 < 4; ++g2)
#pragma unroll
      for (int r = 0; r < 4; ++r) {
        p[g2][r] = __builtin_amdgcn_exp2f(lt[g2][r] - m_new);
        tsum += p[g2][r];
      }
    tsum += __shfl_xor(tsum, 16);
    tsum += __shfl_xor(tsum, 32);
    l_run = l_run * alpha + tsum;
    m_run = m_new;
#pragma unroll
    for (int d = 0; d < 4; ++d) oacc[d] *= alpha;
    // pack P^T B-fragment in-register: pfr[s][j] = p[2s + (j>>2)][j&3]
    short8v pfr[2];
#pragma unroll
    for (int s = 0; s < 2; ++s) {
      union { unsigned u[4]; short8v v; } pu;
      pu.u[0] = cvt_pk_bf16(p[2 * s][0], p[2 * s][1]);
      pu.u[1] = cvt_pk_bf16(p[2 * s][2], p[2 * s][3]);
      pu.u[2] = cvt_pk_bf16(p[2 * s + 1][0], p[2 * s + 1][1]);
      pu.u[3] = cvt_pk_bf16(p[2 * s + 1][2], p[2 * s + 1][3]);
      pfr[s] = pu.v;
    }

    // ---- PV: O^T += V^T * P^T ----
    __builtin_amdgcn_s_setprio(1);
#pragma unroll
    for (int d0 = 0; d0 < 4; ++d0) {
      const unsigned short* vr = &Vbuf[(d0 * 16 + l15) * 64];
#pragma unroll
      for (int s = 0; s < 2; ++s) {
        short8v vf = *reinterpret_cast<const short8v*>(&vr[((s * 4 + g) ^ swz) * 8]);
        oacc[d0] = __builtin_amdgcn_mfma_f32_16x16x32_bf16(vf, pfr[s], oacc[d0], 0, 0, 0);
      }
    }
    __builtin_amdgcn_s_setprio(0);

    asm volatile("" ::: "memory");
    __builtin_amdgcn_s_barrier();
    asm volatile("" ::: "memory");
    mw_cur = mw_nxt;
    cur ^= 1;
  }

  float inv = 1.f / l_run;
#pragma unroll
  for (int d0 = 0; d0 < 4; ++d0) {
    ushort4 o;
    o.x = f2bf(oacc[d0][0] * inv);
    o.y = f2bf(oacc[d0][1] * inv);
    o.z = f2bf(oacc[d0][2] * inv);
    o.w = f2bf(oacc[d0][3] * inv);
    *reinterpret_cast<ushort4*>(&attn[((long)b * S_ + q0) * D_ + h * HD_ + d0 * 16 + g * 4]) = o;
  }
}

// ---------------- launch ----------------
extern "C" void kernel_launch(void* const* d_in, const int* in_sizes, int n_in,
                              void* d_out, int out_size, void* d_ws, size_t ws_size,
                              hipStream_t stream) {
  const float* query = (const float*)d_in[0];
  const float* key   = (const float*)d_in[1];
  const float* value = (const float*)d_in[2];
  const float* mask  = (const float*)d_in[3];
  const float* Wq = (const float*)d_in[4];
  const float* bq = (const float*)d_in[5];
  const float* Wk = (const float*)d_in[6];
  const float* bk = (const float*)d_in[7];
  const float* Wv = (const float*)d_in[8];
  const float* bv = (const float*)d_in[9];
  const float* Wo = (const float*)d_in[10];
  const float* bo = (const float*)d_in[11];

  char* ws = (char*)d_ws;
  unsigned short* XQ  = (unsigned short*)(ws);
  unsigned short* XK  = (unsigned short*)(ws + (16ull << 20));
  unsigned short* XV  = (unsigned short*)(ws + (32ull << 20));
  unsigned short* WQT = (unsigned short*)(ws + (48ull << 20));
  unsigned short* WKT = (unsigned short*)(ws + (50ull << 20));
  unsigned short* WVT = (unsigned short*)(ws + (52ull << 20));
  unsigned short* WOT = (unsigned short*)(ws + (54ull << 20));
  unsigned short* QB  = (unsigned short*)(ws + (56ull << 20));
  unsigned short* KB  = (unsigned short*)(ws + (72ull << 20));
  unsigned short* VT  = (unsigned short*)(ws + (88ull << 20));
  unsigned long long* MBITS = (unsigned long long*)(ws + (16ull << 20));
  unsigned short* ATTN = XQ;

  const int n4 = M_ * D_ / 4;
  cast_bf16_kernel<<<2048, 256, 0, stream>>>(query, XQ, n4);
  cast_bf16_kernel<<<2048, 256, 0, stream>>>(key,   XK, n4);
  cast_bf16_kernel<<<2048, 256, 0, stream>>>(value, XV, n4);

  dim3 tg(D_ / 32, D_ / 32), tb(32, 8);
  transpose_cast_kernel<<<tg, tb, 0, stream>>>(Wq, WQT, D_);
  transpose_cast_kernel<<<tg, tb, 0, stream>>>(Wk, WKT, D_);
  transpose_cast_kernel<<<tg, tb, 0, stream>>>(Wv, WVT, D_);
  transpose_cast_kernel<<<tg, tb, 0, stream>>>(Wo, WOT, D_);

  dim3 gg(M_ / 128, D_ / 128);
  // Q prescale: 1/sqrt(HD) * log2(e) so softmax runs in exp2 domain
  gemm_bt_kernel<0><<<gg, 256, 0, stream>>>(XQ, WQT, bq, QB, M_, D_, D_, 0.18033688011112042f);
  gemm_bt_kernel<0><<<gg, 256, 0, stream>>>(XK, WKT, bk, KB, M_, D_, D_, 1.f);
  gemm_bt_kernel<1><<<gg, 256, 0, stream>>>(XV, WVT, bv, VT, M_, D_, D_, 1.f);

  pack_mask_kernel<<<2048, 256, 0, stream>>>(mask, MBITS, B_ * S_ * S_ / 64);

  dim3 ag(S_ / 64, B_ * H_);
  attn_kernel<<<ag, 256, 0, stream>>>(QB, KB, VT, MBITS, ATTN);

  gemm_bt_kernel<2><<<gg, 256, 0, stream>>>(ATTN, WOT, bo, d_out, M_, D_, D_, 1.f);
}